// Round 2
// baseline (334.816 us; speedup 1.0000x reference)
//
#include <hip/hip_runtime.h>
#include <cstdint>

#define BB   128
#define SS   256
#define NDEPTH 655
#define UU   128
#define VV   512   // 4*UU
#define NPB  32

__device__ __forceinline__ float sigm(float x) {
    return 1.0f / (1.0f + expf(-x));     // accurate: recurrence composes 256 steps
}

// ---------------- context features + sequence_length scalar ----------------
__global__ void context_kernel(const int* __restrict__ last_rule,
                               const int* __restrict__ move_count,
                               const int* __restrict__ node_count,
                               const int* __restrict__ problem_type,
                               float* __restrict__ out, int write_seq) {
    int i = blockIdx.x * blockDim.x + threadIdx.x;
    if (i < BB * 35) {
        int b = i / 35, c = i % 35;
        float v;
        if (c == 0)      v = (float)last_rule[b];
        else if (c == 1) v = (float)move_count[b];
        else if (c == 2) v = (float)node_count[b];
        else             v = (problem_type[b] == (c - 3)) ? 1.0f : 0.0f;
        out[i] = v;
    }
    if (write_seq && i == 0)
        out[(size_t)BB*35 + (size_t)BB*UU + (size_t)BB*SS*UU] = (float)SS;
}

// ---------------- WdWx = W_dense @ Wx  (2620 x 512), base = b_dense@Wx + b_lstm ----
__global__ void wdwx_kernel(const float* __restrict__ Wd,      // [2620,128]
                            const float* __restrict__ Wx,      // [128,512]
                            const float* __restrict__ b_dense, // [128]
                            const float* __restrict__ b_lstm,  // [512]
                            float* __restrict__ WdWx,          // [2620,512]
                            float* __restrict__ base) {        // [512]
    int v  = threadIdx.x;          // 0..511
    int k0 = blockIdx.x * 4;       // 655 blocks, 4 rows each
    const float* wd0 = Wd + (size_t)k0 * UU;   // block-uniform -> scalar loads
    float a0 = 0.f, a1 = 0.f, a2 = 0.f, a3 = 0.f;
    for (int u = 0; u < UU; ++u) {
        float wx = Wx[u * VV + v];             // coalesced, L2-resident
        a0 = fmaf(wd0[u],        wx, a0);
        a1 = fmaf(wd0[UU + u],   wx, a1);
        a2 = fmaf(wd0[2*UU + u], wx, a2);
        a3 = fmaf(wd0[3*UU + u], wx, a3);
    }
    WdWx[(size_t)(k0+0)*VV + v] = a0;
    WdWx[(size_t)(k0+1)*VV + v] = a1;
    WdWx[(size_t)(k0+2)*VV + v] = a2;
    WdWx[(size_t)(k0+3)*VV + v] = a3;
    if (blockIdx.x == 0) {
        float a = 0.f;
        for (int u = 0; u < UU; ++u) a = fmaf(b_dense[u], Wx[u * VV + v], a);
        base[v] = a + b_lstm[v];
    }
}

// ---------------- persistent per-batch LSTM -------------------------------
__global__ __launch_bounds__(512, 2)
void lstm_kernel(const int* __restrict__ bwd,  const int* __restrict__ fwd,
                 const int* __restrict__ lbwd, const int* __restrict__ lfwd,
                 const float* __restrict__ WdWx,   // [2620,512]
                 const float* __restrict__ base,   // [512]
                 const float* __restrict__ Wh,     // [128,512]
                 float* __restrict__ hidden_states, // [B,S,U]
                 float* __restrict__ lstm_vectors) {// [B,U]
    const int b = blockIdx.x;
    const int t = threadIdx.x;     // gate column 0..511

    __shared__ __align__(16) float h_lds[UU];
    __shared__ float act[VV];
    __shared__ int   idx_lds[SS][4];

    // Wh column t -> registers (128 VGPRs)
    float wh[UU];
    #pragma unroll
    for (int u = 0; u < UU; ++u) wh[u] = Wh[u * VV + t];

    // all step indices -> LDS (pre-offset into the 4 concatenated one-hot panels)
    for (int s = t; s < SS; s += 512) {
        idx_lds[s][0] =            bwd [b*SS + s];
        idx_lds[s][1] =   NDEPTH + fwd [b*SS + s];
        idx_lds[s][2] = 2*NDEPTH + lbwd[b*SS + s];
        idx_lds[s][3] = 3*NDEPTH + lfwd[b*SS + s];
    }
    if (t < UU) h_lds[t] = 0.0f;
    float c  = 0.0f;               // cell state, valid for t < UU
    float bb = base[t];
    __syncthreads();

    // prefetch step 0 gather (4 coalesced 2KB rows from L2-resident WdWx)
    float p0 = WdWx[(size_t)idx_lds[0][0] * VV + t];
    float p1 = WdWx[(size_t)idx_lds[0][1] * VV + t];
    float p2 = WdWx[(size_t)idx_lds[0][2] * VV + t];
    float p3 = WdWx[(size_t)idx_lds[0][3] * VV + t];

    for (int s = 0; s < SS; ++s) {
        float z = bb + p0 + p1 + p2 + p3;
        if (s + 1 < SS) {          // prefetch next step under the dot
            p0 = WdWx[(size_t)idx_lds[s+1][0] * VV + t];
            p1 = WdWx[(size_t)idx_lds[s+1][1] * VV + t];
            p2 = WdWx[(size_t)idx_lds[s+1][2] * VV + t];
            p3 = WdWx[(size_t)idx_lds[s+1][3] * VV + t];
        }
        // z += h . Wh[:,t] — 4 partial chains to hide FMA latency
        float z0 = 0.f, z1 = 0.f, z2 = 0.f, z3 = 0.f;
        #pragma unroll
        for (int u = 0; u < UU; u += 4) {
            float4 hv = *(const float4*)(h_lds + u);   // broadcast read
            z0 = fmaf(hv.x, wh[u],   z0);
            z1 = fmaf(hv.y, wh[u+1], z1);
            z2 = fmaf(hv.z, wh[u+2], z2);
            z3 = fmaf(hv.w, wh[u+3], z3);
        }
        z += (z0 + z1) + (z2 + z3);

        // own-column activation: keras order i,f,g,o ; g (cols 256..383) is tanh
        act[t] = (t >= 2*UU && t < 3*UU) ? tanhf(z) : sigm(z);
        __syncthreads();

        if (t < UU) {
            float gi = act[t], gf = act[UU + t], gg = act[2*UU + t], go = act[3*UU + t];
            c = fmaf(gf, c, gi * gg);
            float h = go * tanhf(c);
            h_lds[t] = h;
            hidden_states[((size_t)b * SS + s) * UU + t] = h;
        }
        __syncthreads();
    }
    if (t < UU) lstm_vectors[(size_t)b * UU + t] = h_lds[t];
}

// ---------------------------------------------------------------------------
extern "C" void kernel_launch(void* const* d_in, const int* in_sizes, int n_in,
                              void* d_out, int out_size, void* d_ws, size_t ws_size,
                              hipStream_t stream) {
    const int* move_count   = (const int*)d_in[0];
    // d_in[1] moves_remaining: unused by the reference
    const int* last_rule    = (const int*)d_in[2];
    const int* node_count   = (const int*)d_in[3];
    const int* problem_type = (const int*)d_in[4];
    const int* bwd          = (const int*)d_in[5];
    const int* fwd          = (const int*)d_in[6];
    const int* lbwd         = (const int*)d_in[7];
    const int* lfwd         = (const int*)d_in[8];
    const float* Wd         = (const float*)d_in[9];
    const float* b_dense    = (const float*)d_in[10];
    const float* Wx         = (const float*)d_in[11];
    const float* Wh         = (const float*)d_in[12];
    const float* b_lstm     = (const float*)d_in[13];

    float* out  = (float*)d_out;
    float* WdWx = (float*)d_ws;                        // 2620*512*4 = 5.37 MB
    float* base = WdWx + (size_t)(4 * NDEPTH) * VV;    // +512 floats

    float* lstm_out = out + BB * 35;
    float* hs_out   = lstm_out + BB * UU;
    int write_seq = (out_size > BB*35 + BB*UU + BB*SS*UU) ? 1 : 0;

    context_kernel<<<(BB*35 + 255)/256, 256, 0, stream>>>(
        last_rule, move_count, node_count, problem_type, out, write_seq);
    wdwx_kernel<<<NDEPTH, VV, 0, stream>>>(Wd, Wx, b_dense, b_lstm, WdWx, base);
    lstm_kernel<<<BB, VV, 0, stream>>>(bwd, fwd, lbwd, lfwd, WdWx, base, Wh,
                                       hs_out, lstm_out);
}